// Round 8
// baseline (175.342 us; speedup 1.0000x reference)
//
#include <hip/hip_runtime.h>

// sites [4096,128] f32, consensus [512,128] f32
// out = softmax(-L1dist, axis=-1) -> [4096,512] f32
#define N_SITES 4096
#define M_CONS  512
#define DIM     128

// K1: negated L1 distance. Grid 128x8 = 1024 blocks x 256 threads,
// 16 KB LDS -> 4 blocks/CU = 16 waves/CU = 4 waves/SIMD (latency hiding).
// Block tile 32 rows x 64 cols, split-k x4: wave kg owns quads [kg*8, kg*8+8)
// (dims [kg*32, kg*32+32)). Lane: 4 rows (8i+lr) x 8 consecutive cols
// (lc*8+j), acc[4][8] = 32 VGPR -> big spare-register margin under the
// (256,4) budget of 128.
// Sites staged in LDS [32][128], float4-quad swizzled by (r&7) -> compute
// reads are 8 distinct addresses x 8-way broadcast, conflict-free.
// Consensus NOT staged: 256 KB total, L2-resident on every XCD; each lane
// loads cv[8] per quad from global via one base address + immediate offsets
// (j*512 + q*16 B <= 4080 < 4096 imm limit) -> deep vmcnt pipelining.
// Combine: two half-row passes through the 16 KB LDS ([kg][16][16 quads],
// quad ^ (r&7)); 256 threads sum 4 partials, negate, coalesced float4 store.
__global__ __launch_bounds__(256, 4) void dist_kernel(const float* __restrict__ sites,
                                                      const float* __restrict__ cons,
                                                      float* __restrict__ out) {
    __shared__ __align__(16) float s_sites[32 * 128];   // 16 KB

    const int tid    = threadIdx.x;
    const int rowBlk = blockIdx.x;               // 0..127 (32 rows each)
    const int colBlk = blockIdx.y;               // 0..7   (64 cols each)

    // ---- stage sites tile (16 KB): quad stored at q ^ (r&7)
    {
        const float* g = sites + (size_t)rowBlk * 32 * DIM;
#pragma unroll
        for (int it = 0; it < 4; it++) {
            int f = tid + it * 256;              // 0..1023
            int r = f >> 5, q = f & 31;
            float4 v = *(const float4*)(g + r * DIM + (q << 2));
            *(float4*)&s_sites[r * DIM + ((q ^ (r & 7)) << 2)] = v;
        }
    }

    const int kg   = tid >> 6;                   // wave = k-group 0..3
    const int lane = tid & 63;
    const int lr   = lane >> 3;                  // 0..7
    const int lc   = lane & 7;                   // 0..7

    float acc[4][8];
#pragma unroll
    for (int i = 0; i < 4; i++)
#pragma unroll
        for (int j = 0; j < 8; j++) acc[i][j] = 0.f;

    __syncthreads();

    // ---- compute this k-group's 8 k-quads; cons straight from L2
    const float* cbase = cons + ((size_t)(colBlk * 64 + lc * 8)) * DIM;
#pragma unroll
    for (int qq = 0; qq < 8; qq++) {
        const int q = (kg << 3) + qq;            // 0..31
        float4 cv[8];
#pragma unroll
        for (int j = 0; j < 8; j++)
            cv[j] = *(const float4*)(cbase + j * DIM + (q << 2));
        const int qs_s = ((q ^ lr) << 2);        // site rows of this lane: (r&7)==lr
#pragma unroll
        for (int i = 0; i < 4; i++) {
            float4 sv = *(const float4*)&s_sites[(8 * i + lr) * DIM + qs_s];
#pragma unroll
            for (int j = 0; j < 8; j++) {
                acc[i][j] += fabsf(sv.x - cv[j].x);
                acc[i][j] += fabsf(sv.y - cv[j].y);
                acc[i][j] += fabsf(sv.z - cv[j].z);
                acc[i][j] += fabsf(sv.w - cv[j].w);
            }
        }
    }

    // ---- split-k combine, two half-row passes through the 16 KB LDS
    const int grow0 = rowBlk * 32;
    const int gcol0 = colBlk * 64;
#pragma unroll
    for (int h = 0; h < 2; h++) {
        __syncthreads();                         // sites / previous pass free
        {
            float* base = s_sites + kg * 1024;   // [kg][16 rows][16 quads]
#pragma unroll
            for (int d = 0; d < 2; d++) {
                int i   = 2 * h + d;             // acc row index
                int r16 = 8 * d + lr;            // row within half (r16&7 == lr)
                float4 v0 = { acc[i][0], acc[i][1], acc[i][2], acc[i][3] };
                float4 v1 = { acc[i][4], acc[i][5], acc[i][6], acc[i][7] };
                *(float4*)&base[r16 * 64 + (((lc * 2 + 0) ^ lr) << 2)] = v0;
                *(float4*)&base[r16 * 64 + (((lc * 2 + 1) ^ lr) << 2)] = v1;
            }
        }
        __syncthreads();
        {
            int r16 = tid >> 4;                  // 0..15
            int qd  = tid & 15;                  // 0..15
            const float* b0 = s_sites + r16 * 64 + ((qd ^ (r16 & 7)) << 2);
            float4 a = *(const float4*)(b0);
            float4 b = *(const float4*)(b0 + 1024);
            float4 c = *(const float4*)(b0 + 2048);
            float4 d = *(const float4*)(b0 + 3072);
            float4 s = { -((a.x + b.x) + (c.x + d.x)),
                         -((a.y + b.y) + (c.y + d.y)),
                         -((a.z + b.z) + (c.z + d.z)),
                         -((a.w + b.w) + (c.w + d.w)) };
            *(float4*)&out[(size_t)(grow0 + h * 16 + r16) * M_CONS + gcol0 + (qd << 2)] = s;
        }
    }
}

// K2: in-place row softmax over M_CONS=512. One wave per row, 8 f32/lane.
__global__ __launch_bounds__(256) void softmax_kernel(float* __restrict__ out) {
    const int row  = blockIdx.x * 4 + (threadIdx.x >> 6);
    const int lane = threadIdx.x & 63;
    float* p = out + (size_t)row * M_CONS + lane * 8;

    float4 v0 = *(const float4*)p;
    float4 v1 = *(const float4*)(p + 4);

    float m = fmaxf(fmaxf(fmaxf(v0.x, v0.y), fmaxf(v0.z, v0.w)),
                    fmaxf(fmaxf(v1.x, v1.y), fmaxf(v1.z, v1.w)));
#pragma unroll
    for (int off = 32; off > 0; off >>= 1) m = fmaxf(m, __shfl_xor(m, off));

    float e[8];
    e[0] = __expf(v0.x - m); e[1] = __expf(v0.y - m);
    e[2] = __expf(v0.z - m); e[3] = __expf(v0.w - m);
    e[4] = __expf(v1.x - m); e[5] = __expf(v1.y - m);
    e[6] = __expf(v1.z - m); e[7] = __expf(v1.w - m);

    float s = ((e[0] + e[1]) + (e[2] + e[3])) + ((e[4] + e[5]) + (e[6] + e[7]));
#pragma unroll
    for (int off = 32; off > 0; off >>= 1) s += __shfl_xor(s, off);

    const float inv = 1.f / s;
    float4 o0 = { e[0] * inv, e[1] * inv, e[2] * inv, e[3] * inv };
    float4 o1 = { e[4] * inv, e[5] * inv, e[6] * inv, e[7] * inv };
    *(float4*)p       = o0;
    *(float4*)(p + 4) = o1;
}

extern "C" void kernel_launch(void* const* d_in, const int* in_sizes, int n_in,
                              void* d_out, int out_size, void* d_ws, size_t ws_size,
                              hipStream_t stream) {
    const float* sites = (const float*)d_in[0];
    const float* cons  = (const float*)d_in[1];
    float* out = (float*)d_out;

    dim3 g1(N_SITES / 32, M_CONS / 64);          // 128 x 8 = 1024 blocks, 4/CU
    dist_kernel<<<g1, 256, 0, stream>>>(sites, cons, out);

    softmax_kernel<<<N_SITES / 4, 256, 0, stream>>>(out);
}

// Round 9
// 30.994 us; speedup vs baseline: 5.6573x; 5.6573x over previous
//
#include <hip/hip_runtime.h>

// sites [4096,128] f32, consensus [512,128] f32
// out = softmax(-L1dist, axis=-1) -> [4096,512] f32
#define N_SITES 4096
#define M_CONS  512
#define DIM     128
#define RPB     16        // site rows per block

// Single fused kernel. 256 blocks x 512 threads (1 block/CU; LDS 128 KB).
// Polarity: lane owns consensus column col==tid. Per half (64 dims):
//   - stage consT chunk [512 cols][64 dims] into LDS (coalesced, quad
//     swizzle q^(col&7) -> balanced banks on both write and read)
//   - extract my column -> cv[64] VGPRs (16 x ds_read_b128)
//   - accumulate d[16] over 16 site rows: sites row elements are
//     BLOCK-UNIFORM -> compiler emits s_load -> SGPR operand; inner loop is
//     pure VALU (v_sub + v_add with abs modifier), no LDS/VMEM at all.
// Softmax: block-local (block holds the full 512-wide row in registers):
//   dump d -> LDS[16][512]; wave wv reduces rows {wv, wv+8}: min via
//   shuffle tree, then sum of exp(mn-d) in the same pass; 2 red scalars per
//   row; all lanes then compute exp(mn-d)/sum and store coalesced.
// No split-k combine, no second kernel, no atomics, no device fences.
__global__ __launch_bounds__(512, 1) void fused_kernel(const float* __restrict__ sites,
                                                       const float* __restrict__ cons,
                                                       float* __restrict__ out) {
    __shared__ __align__(16) float lds[32768];   // 128 KB

    const int tid = threadIdx.x;
    const int bid = blockIdx.x;
    const int r0  = bid * RPB;
    const int wv  = tid >> 6;
    const int ln  = tid & 63;

    float d[RPB];
#pragma unroll
    for (int i = 0; i < RPB; i++) d[i] = 0.f;

#pragma unroll 1
    for (int h = 0; h < 2; h++) {
        if (h) __syncthreads();                  // pass h-1 done before overwrite
        // ---- stage consT chunk: cons[:, h*64 .. h*64+64) -> lds[col][64]
        // 8192 float4 quads, 16 per thread, coalesced global reads.
#pragma unroll
        for (int it = 0; it < 16; it++) {
            int f = tid + it * 512;              // 0..8191
            int r = f >> 4;                      // col 0..511
            int q = f & 15;                      // quad within the 64-dim row
            float4 v = *(const float4*)(cons + r * DIM + h * 64 + (q << 2));
            *(float4*)&lds[r * 64 + ((q ^ (r & 7)) << 2)] = v;
        }
        __syncthreads();
        // ---- extract my column into registers (16 x b128, banks balanced)
        float cv[64];
#pragma unroll
        for (int q = 0; q < 16; q++) {
            float4 v = *(const float4*)&lds[tid * 64 + ((q ^ (tid & 7)) << 2)];
            cv[4 * q + 0] = v.x; cv[4 * q + 1] = v.y;
            cv[4 * q + 2] = v.z; cv[4 * q + 3] = v.w;
        }
        // ---- pure-VALU accumulation: 16 rows x 64 dims
        const float* srow = sites + (size_t)r0 * DIM + h * 64;
#pragma unroll
        for (int rr = 0; rr < RPB; rr++) {
#pragma unroll
            for (int k = 0; k < 64; k++) {
                d[rr] += fabsf(srow[rr * DIM + k] - cv[k]);   // srow[..] uniform -> SGPR
            }
        }
    }

    // ---- block-local softmax over the 512 cols held across lanes
    __syncthreads();                             // consT no longer needed
#pragma unroll
    for (int rr = 0; rr < RPB; rr++)
        lds[rr * 512 + tid] = d[rr];             // dmat[16][512], conflict-free
    __syncthreads();

#pragma unroll
    for (int rep = 0; rep < 2; rep++) {          // wave wv owns rows wv, wv+8
        int row = wv + rep * 8;
        const float* p = &lds[row * 512 + ln * 8];
        float4 a = *(const float4*)(p);
        float4 b = *(const float4*)(p + 4);
        float m = fminf(fminf(fminf(a.x, a.y), fminf(a.z, a.w)),
                        fminf(fminf(b.x, b.y), fminf(b.z, b.w)));
#pragma unroll
        for (int off = 32; off > 0; off >>= 1) m = fminf(m, __shfl_xor(m, off));
        float s = ((__expf(m - a.x) + __expf(m - a.y)) + (__expf(m - a.z) + __expf(m - a.w)))
                + ((__expf(m - b.x) + __expf(m - b.y)) + (__expf(m - b.z) + __expf(m - b.w)));
#pragma unroll
        for (int off = 32; off > 0; off >>= 1) s += __shfl_xor(s, off);
        if (ln == 0) {
            lds[8192 + row]      = m;            // red: mn[16]
            lds[8192 + 16 + row] = s;            // red: sum[16]
        }
    }
    __syncthreads();

#pragma unroll
    for (int rr = 0; rr < RPB; rr++) {
        float mn  = lds[8192 + rr];              // broadcast reads (same addr)
        float inv = 1.f / lds[8192 + 16 + rr];
        out[(size_t)(r0 + rr) * M_CONS + tid] = __expf(mn - d[rr]) * inv;
    }
}

extern "C" void kernel_launch(void* const* d_in, const int* in_sizes, int n_in,
                              void* d_out, int out_size, void* d_ws, size_t ws_size,
                              hipStream_t stream) {
    const float* sites = (const float*)d_in[0];
    const float* cons  = (const float*)d_in[1];
    float* out = (float*)d_out;

    fused_kernel<<<N_SITES / RPB, 512, 0, stream>>>(sites, cons, out);  // 256 blocks
}